// Round 8
// baseline (287.155 us; speedup 1.0000x reference)
//
#include <hip/hip_runtime.h>
#include <stdint.h>

#define N_NODES 50000
#define N_EDGES 800000
#define F_IN    512
#define F_HID   128
#define F_OUT   3
#define NBLK_SCAN 196  // ceil(50000/256)

typedef __attribute__((ext_vector_type(8))) short short8;
typedef __attribute__((ext_vector_type(4))) float f32x4;

__device__ __forceinline__ unsigned short f2bf(float f) {
  union { float f; unsigned u; } v; v.f = f;
  unsigned r = v.u + 0x7FFFu + ((v.u >> 16) & 1u);
  return (unsigned short)(r >> 16);
}

// ---- prep: zero degree counters + W1 -> bf16 transposed [n][k] -------------
__global__ __launch_bounds__(256) void k_prep(const float* __restrict__ W1,
                                              unsigned short* __restrict__ W1t,
                                              int* __restrict__ count) {
  int idx = blockIdx.x * 256 + threadIdx.x;
  if (idx < N_NODES) count[idx] = 0;
  if (idx < F_IN * F_HID) {
    int k = idx >> 7;    // W1 is [512][128] row-major
    int n = idx & 127;
    W1t[n * F_IN + k] = f2bf(W1[idx]);
  }
}

__global__ __launch_bounds__(256) void k_hist(const int* __restrict__ dst,
                                              int* __restrict__ count) {
  int e = blockIdx.x * 256 + threadIdx.x;
  if (e < N_EDGES) atomicAdd(&count[dst[e]], 1);
}

// hierarchical scan, stage 1: per-block exclusive prefix + block sums
__global__ __launch_bounds__(256) void k_scan1(const int* __restrict__ count,
                                               int* __restrict__ local_pre,
                                               int* __restrict__ blocksum) {
  __shared__ int s[256];
  int t = threadIdx.x;
  int i = blockIdx.x * 256 + t;
  int v = (i < N_NODES) ? count[i] : 0;
  s[t] = v;
  __syncthreads();
  #pragma unroll
  for (int off = 1; off < 256; off <<= 1) {
    int u = (t >= off) ? s[t - off] : 0;
    __syncthreads();
    s[t] += u;
    __syncthreads();
  }
  if (i < N_NODES) local_pre[i] = s[t] - v;  // exclusive
  if (t == 255) blocksum[blockIdx.x] = s[255];
}

// stage 2+3 merged: every block redundantly scans the 196 block sums in LDS
// (cheap), then finalizes row_ptr / cursor / dinv for its 256 nodes.
__global__ __launch_bounds__(256) void k_scan3(const int* __restrict__ count,
                                               const int* __restrict__ local_pre,
                                               const int* __restrict__ blocksum,
                                               int* __restrict__ row_ptr,
                                               int* __restrict__ cursor,
                                               float* __restrict__ dinv) {
  __shared__ int s[256];
  __shared__ int blockoff;
  int t = threadIdx.x;
  int v = (t < NBLK_SCAN) ? blocksum[t] : 0;
  s[t] = v;
  __syncthreads();
  #pragma unroll
  for (int off = 1; off < 256; off <<= 1) {
    int u = (t >= off) ? s[t - off] : 0;
    __syncthreads();
    s[t] += u;
    __syncthreads();
  }
  if (t == blockIdx.x) blockoff = s[t] - v;  // exclusive prefix of own block
  __syncthreads();
  int i = blockIdx.x * 256 + t;
  if (i < N_NODES) {
    int r = local_pre[i] + blockoff;
    row_ptr[i] = r;
    cursor[i]  = r;
    dinv[i] = rsqrtf((float)(count[i] + 1));
  }
  if (i == 0) row_ptr[N_NODES] = N_EDGES;
}

__global__ __launch_bounds__(256) void k_fill(const int* __restrict__ src,
                                              const int* __restrict__ dst,
                                              int* __restrict__ cursor,
                                              int* __restrict__ csr_src) {
  int e = blockIdx.x * 256 + threadIdx.x;
  if (e >= N_EDGES) return;
  int d = dst[e];
  int pos = atomicAdd(&cursor[d], 1);
  csr_src[pos] = src[e];
}

// ---- GEMM1: h1' = dinv .* (x @ W1)  (bf16 MFMA, f32 acc; bf16 out) ---------
#define BM 128
#define BK 64
#define LPAD 72  // 144 B/row breaks the stride-128B bank conflict

__global__ __launch_bounds__(256) void k_gemm1(const float* __restrict__ x,
                                               const unsigned short* __restrict__ W1t,
                                               const float* __restrict__ dinv,
                                               unsigned short* __restrict__ h1b) {
  __shared__ unsigned short As[BM * LPAD];
  __shared__ unsigned short Bs[F_HID * LPAD];
  const int t = threadIdx.x;
  const int lane = t & 63;
  const int wid = t >> 6;
  const int row0 = blockIdx.x * BM;

  f32x4 acc[2][8];
  #pragma unroll
  for (int i = 0; i < 2; ++i)
    #pragma unroll
    for (int j = 0; j < 8; ++j) acc[i][j] = (f32x4)0.0f;

  const int lane15 = lane & 15;
  const int kgrp = (lane >> 4) << 3;
  const int wrow = wid << 5;

  for (int k0 = 0; k0 < F_IN; k0 += BK) {
    #pragma unroll
    for (int r = 0; r < 8; ++r) {
      int f = (r << 8) + t;
      int row = f >> 4;
      int c4 = (f & 15) << 2;
      int grow = row0 + row;
      grow = grow < N_NODES ? grow : N_NODES - 1;  // clamp tail (store guarded)
      const float4 v = *reinterpret_cast<const float4*>(x + (size_t)grow * F_IN + k0 + c4);
      ushort4 b;
      b.x = f2bf(v.x); b.y = f2bf(v.y); b.z = f2bf(v.z); b.w = f2bf(v.w);
      *reinterpret_cast<ushort4*>(&As[row * LPAD + c4]) = b;
    }
    #pragma unroll
    for (int r = 0; r < 8; ++r) {
      int g = (r << 8) + t;
      int n = g >> 4;
      int c4 = (g & 15) << 2;
      ushort4 wv = *reinterpret_cast<const ushort4*>(W1t + n * F_IN + k0 + c4);
      *reinterpret_cast<ushort4*>(&Bs[n * LPAD + c4]) = wv;
    }
    __syncthreads();
    #pragma unroll
    for (int ks = 0; ks < 2; ++ks) {
      const int kk = (ks << 5) + kgrp;
      short8 a0 = *reinterpret_cast<const short8*>(&As[(wrow + lane15) * LPAD + kk]);
      short8 a1 = *reinterpret_cast<const short8*>(&As[(wrow + 16 + lane15) * LPAD + kk]);
      #pragma unroll
      for (int nr = 0; nr < 8; ++nr) {
        short8 b = *reinterpret_cast<const short8*>(&Bs[(nr * 16 + lane15) * LPAD + kk]);
        acc[0][nr] = __builtin_amdgcn_mfma_f32_16x16x32_bf16(a0, b, acc[0][nr], 0, 0, 0);
        acc[1][nr] = __builtin_amdgcn_mfma_f32_16x16x32_bf16(a1, b, acc[1][nr], 0, 0, 0);
      }
    }
    __syncthreads();
  }
  const int rgrp = (lane >> 4) << 2;
  #pragma unroll
  for (int mr = 0; mr < 2; ++mr) {
    const int rowb = row0 + wrow + mr * 16 + rgrp;
    #pragma unroll
    for (int nr = 0; nr < 8; ++nr) {
      const int col = nr * 16 + lane15;
      #pragma unroll
      for (int r = 0; r < 4; ++r) {
        const int row = rowb + r;
        if (row < N_NODES)
          h1b[(size_t)row * F_HID + col] = f2bf(dinv[row] * acc[mr][nr][r]);
      }
    }
  }
}

// ---- layer-1 gather + bias + ReLU + GEMM2 fused: wave per node ------------
// NEW shape: four 16-lane groups, lane owns 8 features (uint4 = 16 B/lane,
// native dwordx4 -> cannot scalarize). One wave-instruction gathers 4 edges'
// rows; unroll-2 keeps 8 rows in flight. Rows pre-scaled by dinv[src].
__global__ __launch_bounds__(256) void k_agg1_fused(const int* __restrict__ row_ptr,
                                                    const int* __restrict__ csr_src,
                                                    const float* __restrict__ dinv,
                                                    const unsigned short* __restrict__ h1b,
                                                    const float* __restrict__ b1,
                                                    const float* __restrict__ W2,
                                                    float* __restrict__ t2) {
  int t = threadIdx.x;
  int lane = t & 63;
  int node = blockIdx.x * 4 + (t >> 6);  // 50000 = 12500*4, no tail
  int g = lane >> 4;       // edge-group 0..3
  int sl = lane & 15;
  int fl = sl << 3;        // feature base, 8 features per lane
  float dd = dinv[node];
  float a[8] = {0, 0, 0, 0, 0, 0, 0, 0};
  if (g == 0) {  // self loop contributes h1'[node]
    const uint4 sv = *reinterpret_cast<const uint4*>(h1b + (size_t)node * F_HID + fl);
    a[0] = __uint_as_float(sv.x << 16);
    a[1] = __uint_as_float(sv.x & 0xFFFF0000u);
    a[2] = __uint_as_float(sv.y << 16);
    a[3] = __uint_as_float(sv.y & 0xFFFF0000u);
    a[4] = __uint_as_float(sv.z << 16);
    a[5] = __uint_as_float(sv.z & 0xFFFF0000u);
    a[6] = __uint_as_float(sv.w << 16);
    a[7] = __uint_as_float(sv.w & 0xFFFF0000u);
  }
  int start = row_ptr[node], end = row_ptr[node + 1];
  int i = start + g;
  // unroll-2: edges i and i+4 independent -> 8 rows in flight per wave
  for (; i + 4 < end; i += 8) {
    int s0 = csr_src[i];
    int s1 = csr_src[i + 4];
    const uint4 v0 = *reinterpret_cast<const uint4*>(h1b + (size_t)s0 * F_HID + fl);
    const uint4 v1 = *reinterpret_cast<const uint4*>(h1b + (size_t)s1 * F_HID + fl);
    a[0] += __uint_as_float(v0.x << 16);
    a[1] += __uint_as_float(v0.x & 0xFFFF0000u);
    a[2] += __uint_as_float(v0.y << 16);
    a[3] += __uint_as_float(v0.y & 0xFFFF0000u);
    a[4] += __uint_as_float(v0.z << 16);
    a[5] += __uint_as_float(v0.z & 0xFFFF0000u);
    a[6] += __uint_as_float(v0.w << 16);
    a[7] += __uint_as_float(v0.w & 0xFFFF0000u);
    a[0] += __uint_as_float(v1.x << 16);
    a[1] += __uint_as_float(v1.x & 0xFFFF0000u);
    a[2] += __uint_as_float(v1.y << 16);
    a[3] += __uint_as_float(v1.y & 0xFFFF0000u);
    a[4] += __uint_as_float(v1.z << 16);
    a[5] += __uint_as_float(v1.z & 0xFFFF0000u);
    a[6] += __uint_as_float(v1.w << 16);
    a[7] += __uint_as_float(v1.w & 0xFFFF0000u);
  }
  for (; i < end; i += 4) {
    int s = csr_src[i];
    const uint4 v = *reinterpret_cast<const uint4*>(h1b + (size_t)s * F_HID + fl);
    a[0] += __uint_as_float(v.x << 16);
    a[1] += __uint_as_float(v.x & 0xFFFF0000u);
    a[2] += __uint_as_float(v.y << 16);
    a[3] += __uint_as_float(v.y & 0xFFFF0000u);
    a[4] += __uint_as_float(v.z << 16);
    a[5] += __uint_as_float(v.z & 0xFFFF0000u);
    a[6] += __uint_as_float(v.w << 16);
    a[7] += __uint_as_float(v.w & 0xFFFF0000u);
  }
  // combine the 4 edge-groups (same sl across groups)
  #pragma unroll
  for (int j = 0; j < 8; ++j) {
    a[j] += __shfl_xor(a[j], 16);
    a[j] += __shfl_xor(a[j], 32);
  }
  // features = b1 + dd * acc; relu
  const float4 bb0 = *reinterpret_cast<const float4*>(b1 + fl);
  const float4 bb1 = *reinterpret_cast<const float4*>(b1 + fl + 4);
  float v0 = fmaxf(fmaf(dd, a[0], bb0.x), 0.0f);
  float v1 = fmaxf(fmaf(dd, a[1], bb0.y), 0.0f);
  float v2 = fmaxf(fmaf(dd, a[2], bb0.z), 0.0f);
  float v3 = fmaxf(fmaf(dd, a[3], bb0.w), 0.0f);
  float v4 = fmaxf(fmaf(dd, a[4], bb1.x), 0.0f);
  float v5 = fmaxf(fmaf(dd, a[5], bb1.y), 0.0f);
  float v6 = fmaxf(fmaf(dd, a[6], bb1.z), 0.0f);
  float v7 = fmaxf(fmaf(dd, a[7], bb1.w), 0.0f);
  // 128->3 dot products; W2 is [128][3] row-major; store t2' = dinv[node]*t2
  const float* w2r = W2 + fl * 3;
  #pragma unroll
  for (int c = 0; c < 3; ++c) {
    float p = v0 * w2r[c]      + v1 * w2r[3 + c]  + v2 * w2r[6 + c]  + v3 * w2r[9 + c]
            + v4 * w2r[12 + c] + v5 * w2r[15 + c] + v6 * w2r[18 + c] + v7 * w2r[21 + c];
    p += __shfl_down(p, 8);
    p += __shfl_down(p, 4);
    p += __shfl_down(p, 2);
    p += __shfl_down(p, 1);
    if (lane == 0) t2[(size_t)node * 3 + c] = dd * p;
  }
}

// ---- layer-2 gather: 16 lanes per node; t2 rows pre-scaled -----------------
__global__ __launch_bounds__(256) void k_agg2(const int* __restrict__ row_ptr,
                                              const int* __restrict__ csr_src,
                                              const float* __restrict__ dinv,
                                              const float* __restrict__ t2,
                                              const float* __restrict__ b2,
                                              float* __restrict__ out) {
  int t = threadIdx.x;
  int node = blockIdx.x * 16 + (t >> 4);
  if (node >= N_NODES) return;
  int sl = t & 15;
  float a0 = 0.f, a1 = 0.f, a2 = 0.f;
  int start = row_ptr[node], end = row_ptr[node + 1];
  for (int i = start + sl; i < end; i += 16) {
    int s = csr_src[i];
    a0 += t2[s * 3 + 0];
    a1 += t2[s * 3 + 1];
    a2 += t2[s * 3 + 2];
  }
  #pragma unroll
  for (int off = 8; off > 0; off >>= 1) {
    a0 += __shfl_down(a0, off);
    a1 += __shfl_down(a1, off);
    a2 += __shfl_down(a2, off);
  }
  if (sl == 0) {
    float dd = dinv[node];
    out[node * 3 + 0] = fmaf(dd, t2[node * 3 + 0] + a0, b2[0]);
    out[node * 3 + 1] = fmaf(dd, t2[node * 3 + 1] + a1, b2[1]);
    out[node * 3 + 2] = fmaf(dd, t2[node * 3 + 2] + a2, b2[2]);
  }
}

extern "C" void kernel_launch(void* const* d_in, const int* in_sizes, int n_in,
                              void* d_out, int out_size, void* d_ws, size_t ws_size,
                              hipStream_t stream) {
  const float* x  = (const float*)d_in[0];
  const int*   ei = (const int*)d_in[1];
  const float* W1 = (const float*)d_in[2];
  const float* b1 = (const float*)d_in[3];
  const float* W2 = (const float*)d_in[4];
  const float* b2 = (const float*)d_in[5];
  const int* src = ei;
  const int* dst = ei + N_EDGES;
  float* out = (float*)d_out;

  char* ws = (char*)d_ws;
  // ws layout (16B aligned):
  float*          dinv    = (float*)(ws + 0);          // 200000 B
  int*            count   = (int*)  (ws + 200704);     // 200000 B
  int*            cursor  = (int*)  (ws + 401408);     // 200000 B
  int*            row_ptr = (int*)  (ws + 602112);     // 200004 B
  int*            csr_src = (int*)  (ws + 802816);     // 3200000 B
  unsigned short* W1t     = (unsigned short*)(ws + 4002816);  // 131072 B
  float*          t2      = (float*)(ws + 4133888);    // 600000 B
  int*            local_pre = (int*)(ws + 4733952);    // 200000 B
  int*            blocksum  = (int*)(ws + 4935680);    // 784 B
  unsigned short* h1b     = (unsigned short*)(ws + 4937728);  // 12800000 B (end ~17.7 MB)

  k_prep  <<<(F_IN * F_HID + 255) / 256, 256, 0, stream>>>(W1, W1t, count);
  k_hist  <<<(N_EDGES + 255) / 256, 256, 0, stream>>>(dst, count);
  k_scan1 <<<NBLK_SCAN, 256, 0, stream>>>(count, local_pre, blocksum);
  k_scan3 <<<NBLK_SCAN, 256, 0, stream>>>(count, local_pre, blocksum, row_ptr, cursor, dinv);
  k_fill  <<<(N_EDGES + 255) / 256, 256, 0, stream>>>(src, dst, cursor, csr_src);
  k_gemm1 <<<(N_NODES + BM - 1) / BM, 256, 0, stream>>>(x, W1t, dinv, h1b);
  k_agg1_fused<<<N_NODES / 4, 256, 0, stream>>>(row_ptr, csr_src, dinv, h1b, b1, W2, t2);
  k_agg2  <<<(N_NODES + 15) / 16, 256, 0, stream>>>(row_ptr, csr_src, dinv, t2, b2, out);
}

// Round 9
// 186.775 us; speedup vs baseline: 1.5374x; 1.5374x over previous
//
#include <hip/hip_runtime.h>
#include <stdint.h>

#define N_NODES 50000
#define N_EDGES 800000
#define F_IN    512
#define F_HID   128
#define F_OUT   3
#define NBLK_SCAN 196  // ceil(50000/256)

typedef __attribute__((ext_vector_type(8))) short short8;
typedef __attribute__((ext_vector_type(4))) float f32x4;

__device__ __forceinline__ unsigned short f2bf(float f) {
  union { float f; unsigned u; } v; v.f = f;
  unsigned r = v.u + 0x7FFFu + ((v.u >> 16) & 1u);
  return (unsigned short)(r >> 16);
}

// ---- prep: zero degree counters + W1 -> bf16 transposed [n][k] -------------
__global__ __launch_bounds__(256) void k_prep(const float* __restrict__ W1,
                                              unsigned short* __restrict__ W1t,
                                              int* __restrict__ count) {
  int idx = blockIdx.x * 256 + threadIdx.x;
  if (idx < N_NODES) count[idx] = 0;
  if (idx < F_IN * F_HID) {
    int k = idx >> 7;    // W1 is [512][128] row-major
    int n = idx & 127;
    W1t[n * F_IN + k] = f2bf(W1[idx]);
  }
}

__global__ __launch_bounds__(256) void k_hist(const int* __restrict__ dst,
                                              int* __restrict__ count) {
  int e = blockIdx.x * 256 + threadIdx.x;
  if (e < N_EDGES) atomicAdd(&count[dst[e]], 1);
}

// hierarchical scan, stage 1: per-block exclusive prefix + block sums
__global__ __launch_bounds__(256) void k_scan1(const int* __restrict__ count,
                                               int* __restrict__ local_pre,
                                               int* __restrict__ blocksum) {
  __shared__ int s[256];
  int t = threadIdx.x;
  int i = blockIdx.x * 256 + t;
  int v = (i < N_NODES) ? count[i] : 0;
  s[t] = v;
  __syncthreads();
  #pragma unroll
  for (int off = 1; off < 256; off <<= 1) {
    int u = (t >= off) ? s[t - off] : 0;
    __syncthreads();
    s[t] += u;
    __syncthreads();
  }
  if (i < N_NODES) local_pre[i] = s[t] - v;  // exclusive
  if (t == 255) blocksum[blockIdx.x] = s[255];
}

// stage 2+3 merged: every block redundantly scans the 196 block sums in LDS,
// then finalizes row_ptr / cursor / dinv for its 256 nodes.
__global__ __launch_bounds__(256) void k_scan3(const int* __restrict__ count,
                                               const int* __restrict__ local_pre,
                                               const int* __restrict__ blocksum,
                                               int* __restrict__ row_ptr,
                                               int* __restrict__ cursor,
                                               float* __restrict__ dinv) {
  __shared__ int s[256];
  __shared__ int blockoff;
  int t = threadIdx.x;
  int v = (t < NBLK_SCAN) ? blocksum[t] : 0;
  s[t] = v;
  __syncthreads();
  #pragma unroll
  for (int off = 1; off < 256; off <<= 1) {
    int u = (t >= off) ? s[t - off] : 0;
    __syncthreads();
    s[t] += u;
    __syncthreads();
  }
  if (t == blockIdx.x) blockoff = s[t] - v;  // exclusive prefix of own block
  __syncthreads();
  int i = blockIdx.x * 256 + t;
  if (i < N_NODES) {
    int r = local_pre[i] + blockoff;
    row_ptr[i] = r;
    cursor[i]  = r;
    dinv[i] = rsqrtf((float)(count[i] + 1));
  }
  if (i == 0) row_ptr[N_NODES] = N_EDGES;
}

__global__ __launch_bounds__(256) void k_fill(const int* __restrict__ src,
                                              const int* __restrict__ dst,
                                              int* __restrict__ cursor,
                                              int* __restrict__ csr_src) {
  int e = blockIdx.x * 256 + threadIdx.x;
  if (e >= N_EDGES) return;
  int d = dst[e];
  int pos = atomicAdd(&cursor[d], 1);
  csr_src[pos] = src[e];
}

// ---- GEMM1: h1' = dinv .* (x @ W1)  (bf16 MFMA, f32 acc; bf16 out) ---------
// BM=64: 782 blocks -> 3.05 blocks/CU (BM=128 gave 391 -> 1.53/CU, ~1.9x
// tail imbalance). Each wave: one 16-row A-fragment, 8 col-fragments.
#define BM 64
#define BK 64
#define LPAD 72  // 144 B/row breaks the stride-128B bank conflict

__global__ __launch_bounds__(256) void k_gemm1(const float* __restrict__ x,
                                               const unsigned short* __restrict__ W1t,
                                               const float* __restrict__ dinv,
                                               unsigned short* __restrict__ h1b) {
  __shared__ unsigned short As[BM * LPAD];
  __shared__ unsigned short Bs[F_HID * LPAD];
  const int t = threadIdx.x;
  const int lane = t & 63;
  const int wid = t >> 6;
  const int row0 = blockIdx.x * BM;

  f32x4 acc[8];
  #pragma unroll
  for (int j = 0; j < 8; ++j) acc[j] = (f32x4)0.0f;

  const int lane15 = lane & 15;
  const int kgrp = (lane >> 4) << 3;
  const int wrow = wid << 4;  // wave owns 16 rows

  for (int k0 = 0; k0 < F_IN; k0 += BK) {
    // stage A: 64 rows x 64 f32 -> bf16 (1024 float4, 4 rounds x 256 thr)
    #pragma unroll
    for (int r = 0; r < 4; ++r) {
      int f = (r << 8) + t;
      int row = f >> 4;
      int c4 = (f & 15) << 2;
      int grow = row0 + row;
      grow = grow < N_NODES ? grow : N_NODES - 1;  // clamp tail (store guarded)
      const float4 v = *reinterpret_cast<const float4*>(x + (size_t)grow * F_IN + k0 + c4);
      ushort4 b;
      b.x = f2bf(v.x); b.y = f2bf(v.y); b.z = f2bf(v.z); b.w = f2bf(v.w);
      *reinterpret_cast<ushort4*>(&As[row * LPAD + c4]) = b;
    }
    // stage B: W1t[n][k0..k0+64), already bf16, already [col][k]
    #pragma unroll
    for (int r = 0; r < 8; ++r) {
      int g = (r << 8) + t;
      int n = g >> 4;
      int c4 = (g & 15) << 2;
      ushort4 wv = *reinterpret_cast<const ushort4*>(W1t + n * F_IN + k0 + c4);
      *reinterpret_cast<ushort4*>(&Bs[n * LPAD + c4]) = wv;
    }
    __syncthreads();
    #pragma unroll
    for (int ks = 0; ks < 2; ++ks) {
      const int kk = (ks << 5) + kgrp;
      short8 a0 = *reinterpret_cast<const short8*>(&As[(wrow + lane15) * LPAD + kk]);
      #pragma unroll
      for (int nr = 0; nr < 8; ++nr) {
        short8 b = *reinterpret_cast<const short8*>(&Bs[(nr * 16 + lane15) * LPAD + kk]);
        acc[nr] = __builtin_amdgcn_mfma_f32_16x16x32_bf16(a0, b, acc[nr], 0, 0, 0);
      }
    }
    __syncthreads();
  }
  const int rgrp = (lane >> 4) << 2;
  const int rowb = row0 + wrow + rgrp;
  #pragma unroll
  for (int nr = 0; nr < 8; ++nr) {
    const int col = nr * 16 + lane15;
    #pragma unroll
    for (int r = 0; r < 4; ++r) {
      const int row = rowb + r;
      if (row < N_NODES)
        h1b[(size_t)row * F_HID + col] = f2bf(dinv[row] * acc[nr][r]);
    }
  }
}

// ---- layer-1 gather + bias + ReLU + GEMM2 fused: wave per node ------------
// R7-proven shape (62.4 us measured): two 32-lane groups, 4 features/lane,
// stride-2 interleave, bf16 rows via uint2, unroll-4, rows pre-scaled by
// dinv[src]. Empirical law (R4+R8, measured twice): gather instructions
// spanning 4 distinct random rows run ~2.5x slower than 2 rows -> keep
// 32-lane groups, <=8 B/lane. Only change vs R7: t2 stored as padded float4.
__global__ __launch_bounds__(256) void k_agg1_fused(const int* __restrict__ row_ptr,
                                                    const int* __restrict__ csr_src,
                                                    const float* __restrict__ dinv,
                                                    const unsigned short* __restrict__ h1b,
                                                    const float* __restrict__ b1,
                                                    const float* __restrict__ W2,
                                                    float* __restrict__ t2p) {
  int t = threadIdx.x;
  int lane = t & 63;
  int node = blockIdx.x * 4 + (t >> 6);  // 50000 = 12500*4, no tail
  int g = lane >> 5;
  int fl = (lane & 31) << 2;
  float dd = dinv[node];
  f32x4 acc = (f32x4)0.0f;
  if (g == 0) {  // self loop contributes h1'[node]
    const uint2 sv = *reinterpret_cast<const uint2*>(h1b + (size_t)node * F_HID + fl);
    acc[0] = __uint_as_float(sv.x << 16);
    acc[1] = __uint_as_float(sv.x & 0xFFFF0000u);
    acc[2] = __uint_as_float(sv.y << 16);
    acc[3] = __uint_as_float(sv.y & 0xFFFF0000u);
  }
  int start = row_ptr[node], end = row_ptr[node + 1];
  int i = start + g;
  // unroll-4: edges i, i+2, i+4, i+6 -> 4 rows in flight per group
  for (; i + 6 < end; i += 8) {
    int s0 = csr_src[i];
    int s1 = csr_src[i + 2];
    int s2 = csr_src[i + 4];
    int s3 = csr_src[i + 6];
    const uint2 v0 = *reinterpret_cast<const uint2*>(h1b + (size_t)s0 * F_HID + fl);
    const uint2 v1 = *reinterpret_cast<const uint2*>(h1b + (size_t)s1 * F_HID + fl);
    const uint2 v2 = *reinterpret_cast<const uint2*>(h1b + (size_t)s2 * F_HID + fl);
    const uint2 v3 = *reinterpret_cast<const uint2*>(h1b + (size_t)s3 * F_HID + fl);
    acc[0] += __uint_as_float(v0.x << 16);
    acc[1] += __uint_as_float(v0.x & 0xFFFF0000u);
    acc[2] += __uint_as_float(v0.y << 16);
    acc[3] += __uint_as_float(v0.y & 0xFFFF0000u);
    acc[0] += __uint_as_float(v1.x << 16);
    acc[1] += __uint_as_float(v1.x & 0xFFFF0000u);
    acc[2] += __uint_as_float(v1.y << 16);
    acc[3] += __uint_as_float(v1.y & 0xFFFF0000u);
    acc[0] += __uint_as_float(v2.x << 16);
    acc[1] += __uint_as_float(v2.x & 0xFFFF0000u);
    acc[2] += __uint_as_float(v2.y << 16);
    acc[3] += __uint_as_float(v2.y & 0xFFFF0000u);
    acc[0] += __uint_as_float(v3.x << 16);
    acc[1] += __uint_as_float(v3.x & 0xFFFF0000u);
    acc[2] += __uint_as_float(v3.y << 16);
    acc[3] += __uint_as_float(v3.y & 0xFFFF0000u);
  }
  for (; i < end; i += 2) {
    int s = csr_src[i];
    const uint2 v = *reinterpret_cast<const uint2*>(h1b + (size_t)s * F_HID + fl);
    acc[0] += __uint_as_float(v.x << 16);
    acc[1] += __uint_as_float(v.x & 0xFFFF0000u);
    acc[2] += __uint_as_float(v.y << 16);
    acc[3] += __uint_as_float(v.y & 0xFFFF0000u);
  }
  // combine the two edge-groups: lanes 0-31 += lanes 32-63
  #pragma unroll
  for (int j = 0; j < 4; ++j) {
    float o = __shfl(acc[j], (lane & 31) + 32);
    acc[j] += o;
  }
  // features = b1 + dd * acc; relu
  const float4 bb = *reinterpret_cast<const float4*>(b1 + fl);
  float v0 = fmaxf(fmaf(dd, acc[0], bb.x), 0.0f);
  float v1 = fmaxf(fmaf(dd, acc[1], bb.y), 0.0f);
  float v2 = fmaxf(fmaf(dd, acc[2], bb.z), 0.0f);
  float v3 = fmaxf(fmaf(dd, acc[3], bb.w), 0.0f);
  // 128->3 dot products; W2 is [128][3] row-major; store t2' = dinv[node]*t2
  const float* w2r = W2 + fl * 3;
  float pr[3];
  #pragma unroll
  for (int c = 0; c < 3; ++c) {
    float p = v0 * w2r[c] + v1 * w2r[3 + c] + v2 * w2r[6 + c] + v3 * w2r[9 + c];
    p += __shfl_down(p, 16);
    p += __shfl_down(p, 8);
    p += __shfl_down(p, 4);
    p += __shfl_down(p, 2);
    p += __shfl_down(p, 1);
    pr[c] = p;
  }
  if (lane == 0) {
    float4 o;
    o.x = dd * pr[0]; o.y = dd * pr[1]; o.z = dd * pr[2]; o.w = 0.0f;
    *reinterpret_cast<float4*>(t2p + (size_t)node * 4) = o;
  }
}

// ---- layer-2 gather: 16 lanes per node; t2p rows padded to 16 B -> one
// dwordx4 per edge (was 3 dependent dword loads).
__global__ __launch_bounds__(256) void k_agg2(const int* __restrict__ row_ptr,
                                              const int* __restrict__ csr_src,
                                              const float* __restrict__ dinv,
                                              const float* __restrict__ t2p,
                                              const float* __restrict__ b2,
                                              float* __restrict__ out) {
  int t = threadIdx.x;
  int node = blockIdx.x * 16 + (t >> 4);
  if (node >= N_NODES) return;
  int sl = t & 15;
  float a0 = 0.f, a1 = 0.f, a2 = 0.f;
  int start = row_ptr[node], end = row_ptr[node + 1];
  for (int i = start + sl; i < end; i += 16) {
    int s = csr_src[i];
    const float4 v = *reinterpret_cast<const float4*>(t2p + (size_t)s * 4);
    a0 += v.x; a1 += v.y; a2 += v.z;
  }
  #pragma unroll
  for (int off = 8; off > 0; off >>= 1) {
    a0 += __shfl_down(a0, off);
    a1 += __shfl_down(a1, off);
    a2 += __shfl_down(a2, off);
  }
  if (sl == 0) {
    float dd = dinv[node];
    const float4 sv = *reinterpret_cast<const float4*>(t2p + (size_t)node * 4);
    out[node * 3 + 0] = fmaf(dd, sv.x + a0, b2[0]);
    out[node * 3 + 1] = fmaf(dd, sv.y + a1, b2[1]);
    out[node * 3 + 2] = fmaf(dd, sv.z + a2, b2[2]);
  }
}

extern "C" void kernel_launch(void* const* d_in, const int* in_sizes, int n_in,
                              void* d_out, int out_size, void* d_ws, size_t ws_size,
                              hipStream_t stream) {
  const float* x  = (const float*)d_in[0];
  const int*   ei = (const int*)d_in[1];
  const float* W1 = (const float*)d_in[2];
  const float* b1 = (const float*)d_in[3];
  const float* W2 = (const float*)d_in[4];
  const float* b2 = (const float*)d_in[5];
  const int* src = ei;
  const int* dst = ei + N_EDGES;
  float* out = (float*)d_out;

  char* ws = (char*)d_ws;
  // ws layout (16B aligned):
  float*          dinv    = (float*)(ws + 0);          // 200000 B
  int*            count   = (int*)  (ws + 200704);     // 200000 B
  int*            cursor  = (int*)  (ws + 401408);     // 200000 B
  int*            row_ptr = (int*)  (ws + 602112);     // 200004 B
  int*            csr_src = (int*)  (ws + 802816);     // 3200000 B
  unsigned short* W1t     = (unsigned short*)(ws + 4002816);  // 131072 B
  float*          t2p     = (float*)(ws + 4133888);    // 800000 B (padded 4/node)
  int*            local_pre = (int*)(ws + 4934656);    // 200000 B
  int*            blocksum  = (int*)(ws + 5134656);    // 784 B
  unsigned short* h1b     = (unsigned short*)(ws + 5135872);  // 12800000 B (end ~17.9 MB)

  k_prep  <<<(F_IN * F_HID + 255) / 256, 256, 0, stream>>>(W1, W1t, count);
  k_hist  <<<(N_EDGES + 255) / 256, 256, 0, stream>>>(dst, count);
  k_scan1 <<<NBLK_SCAN, 256, 0, stream>>>(count, local_pre, blocksum);
  k_scan3 <<<NBLK_SCAN, 256, 0, stream>>>(count, local_pre, blocksum, row_ptr, cursor, dinv);
  k_fill  <<<(N_EDGES + 255) / 256, 256, 0, stream>>>(src, dst, cursor, csr_src);
  k_gemm1 <<<(N_NODES + BM - 1) / BM, 256, 0, stream>>>(x, W1t, dinv, h1b);
  k_agg1_fused<<<N_NODES / 4, 256, 0, stream>>>(row_ptr, csr_src, dinv, h1b, b1, W2, t2p);
  k_agg2  <<<(N_NODES + 15) / 16, 256, 0, stream>>>(row_ptr, csr_src, dinv, t2p, b2, out);
}